// Round 1
// 715.497 us; speedup vs baseline: 1.0437x; 1.0437x over previous
//
#include <hip/hip_runtime.h>
#include <hip/hip_bf16.h>

#define N_NODES 100000
#define E_EDGES 1600000
#define T_TGT   4096
#define P_PAIRS 131072
#define NCHUNK  98   // ceil(N_NODES/1024)

typedef __bf16 bf16x8 __attribute__((ext_vector_type(8)));
typedef float  f32x4  __attribute__((ext_vector_type(4)));

__device__ __forceinline__ float b2f(unsigned short u) {
  unsigned int x = ((unsigned int)u) << 16;
  return __builtin_bit_cast(float, x);
}
__device__ __forceinline__ unsigned short f2b(float f) {
  unsigned int x = __builtin_bit_cast(unsigned int, f);
  x += 0x7fffu + ((x >> 16) & 1u);
  return (unsigned short)(x >> 16);
}
__device__ __forceinline__ bf16x8 ld8(const unsigned short* p) {
  return *reinterpret_cast<const bf16x8*>(p);
}
__device__ __forceinline__ f32x4 mfma16(bf16x8 a, bf16x8 b, f32x4 c) {
  return __builtin_amdgcn_mfma_f32_16x16x32_bf16(a, b, c, 0, 0, 0);
}
// dual-dtype scalar read: element i of a float tensor that is fp32 or bf16
__device__ __forceinline__ float ldf(const void* p, size_t i, bool f32) {
  return f32 ? ((const float*)p)[i] : b2f(((const unsigned short*)p)[i]);
}
// dual-dtype 8-element A/B fragment load (elem = element offset, 8 contiguous)
__device__ __forceinline__ bf16x8 ld8d(const void* p, size_t elem, bool f32) {
  if (!f32) return ld8((const unsigned short*)p + elem);
  const float* q = (const float*)p + elem;
  union { bf16x8 v; unsigned short s[8]; } u;
#pragma unroll
  for (int j = 0; j < 8; ++j) u.s[j] = f2b(q[j]);
  return u.v;
}

// ---------------- dtype sniff ----------------
__global__ void k_sniff(const unsigned int* __restrict__ x, int* __restrict__ dflag) {
  unsigned int w = x[(size_t)threadIdx.x * 24001];
  int e = (w >> 7) & 0xff;
  if (e < 90 || e > 140) atomicAdd(dflag, 1);
}

// ---------------- graph prep ----------------
// hist now also records each edge's rank within its dst bucket (the atomic
// return value we previously discarded) so k_fill needs no atomics.
__global__ void k_hist(const int* __restrict__ dst, int* __restrict__ cnt,
                       int* __restrict__ rank) {
  for (int e = blockIdx.x * blockDim.x + threadIdx.x; e < E_EDGES;
       e += gridDim.x * blockDim.x) {
    int d = dst[e];
    rank[e] = atomicAdd(&cnt[d], 1);
  }
}

__global__ void k_deginv(const int* __restrict__ cnt, float* __restrict__ dinv) {
  int n = blockIdx.x * blockDim.x + threadIdx.x;
  if (n < N_NODES) dinv[n] = 1.0f / (float)max(cnt[n], 1);
}

__global__ void k_scan_a(const int* __restrict__ cnt, int* __restrict__ part) {
  __shared__ int sd[256];
  int t = threadIdx.x;
  int base = blockIdx.x * 1024 + t * 4;
  int s = 0;
  for (int j = 0; j < 4; ++j) {
    int idx = base + j;
    if (idx < N_NODES) s += cnt[idx];
  }
  sd[t] = s; __syncthreads();
  for (int off = 128; off > 0; off >>= 1) {
    if (t < off) sd[t] += sd[t + off];
    __syncthreads();
  }
  if (t == 0) part[blockIdx.x] = sd[0];
}

__global__ void k_scan_b(int* __restrict__ part, int* __restrict__ offs) {
  int run = 0;
  for (int i = 0; i < NCHUNK; ++i) { int v = part[i]; part[i] = run; run += v; }
  offs[N_NODES] = run;
}

__global__ void k_scan_c(const int* __restrict__ cnt, const int* __restrict__ part,
                         int* __restrict__ offs) {
  __shared__ int sd[256];
  int t = threadIdx.x;
  int base = blockIdx.x * 1024 + t * 4;
  int v[4]; int s = 0;
  for (int j = 0; j < 4; ++j) {
    int idx = base + j;
    v[j] = (idx < N_NODES) ? cnt[idx] : 0;
    s += v[j];
  }
  sd[t] = s; __syncthreads();
  for (int off = 1; off < 256; off <<= 1) {
    int x = (t >= off) ? sd[t - off] : 0;
    __syncthreads();
    sd[t] += x;
    __syncthreads();
  }
  int excl = sd[t] - s + part[blockIdx.x];
  for (int j = 0; j < 4; ++j) {
    int idx = base + j;
    if (idx < N_NODES) { offs[idx] = excl; excl += v[j]; }
  }
}

// pure scatter, no atomics, no dependent chain: full MLP on the stores
__global__ void k_fill(const int* __restrict__ src, const int* __restrict__ dst,
                       const int* __restrict__ offs, const int* __restrict__ rank,
                       int* __restrict__ csr) {
  for (int e = blockIdx.x * blockDim.x + threadIdx.x; e < E_EDGES;
       e += gridDim.x * blockDim.x) {
    csr[offs[dst[e]] + rank[e]] = src[e];
  }
}

// ---------------- small utils (dual-dtype reads) ----------------
__global__ void k_transpose(const void* __restrict__ in,
                            unsigned short* __restrict__ out, int K, int Nc,
                            int Kpad, int total, const int* __restrict__ dflag) {
  bool f32 = *dflag > 128;
  int i = blockIdx.x * blockDim.x + threadIdx.x;
  if (i >= total) return;
  int n = i / Kpad, k = i % Kpad;
  out[i] = (k < K) ? f2b(ldf(in, (size_t)k * Nc + n, f32)) : (unsigned short)0;
}

// w1T' for predictor: [256 hidden][160 k] bf16.
// k<128 -> Wp1[k][h] (ctx part); 128..135 -> Wp1[k+64][h] (pe_s|pe_t); else 0.
// (the z block rows 128..191 are folded into zconst)
__global__ void k_tr_wp1(const void* __restrict__ in, unsigned short* __restrict__ out,
                         const int* __restrict__ dflag) {
  bool f32 = *dflag > 128;
  int i = blockIdx.x * blockDim.x + threadIdx.x;
  if (i >= 256 * 160) return;
  int n = i / 160, k = i % 160;
  float v = 0.f;
  if (k < 128)      v = ldf(in, (size_t)k * 256 + n, f32);
  else if (k < 136) v = ldf(in, (size_t)(k + 64) * 256 + n, f32);
  out[i] = f2b(v);
}

// w2T' : [128 out][256 k'] bf16 with sigma-permuted hidden index:
// sigma(k) = (k%16)*16 + k/16 (involution). Matches shH's packed-store layout.
__global__ void k_tr_wp2(const void* __restrict__ in, unsigned short* __restrict__ out,
                         const int* __restrict__ dflag) {
  bool f32 = *dflag > 128;
  int i = blockIdx.x * blockDim.x + threadIdx.x;
  if (i >= 128 * 256) return;
  int n = i / 256, k = i % 256;
  int ks = (k & 15) * 16 + (k >> 4);
  out[i] = f2b(ldf(in, (size_t)ks * 128 + n, f32));
}

// zconst[h] = b1[h] + sum_k z[k] * Wp1[128+k][h]  (z is row-broadcast)
__global__ void k_zconst(const void* __restrict__ z, const void* __restrict__ wp1,
                         const void* __restrict__ b1, float* __restrict__ zc,
                         const int* __restrict__ dflag) {
  bool f32 = *dflag > 128;
  int h = threadIdx.x;
  float acc = ldf(b1, h, f32);
  for (int k = 0; k < 64; ++k)
    acc += ldf(z, k, f32) * ldf(wp1, (size_t)(128 + k) * 256 + h, f32);
  zc[h] = acc;
}

__global__ void k_pe(const void* __restrict__ pos, const void* __restrict__ wpe,
                     unsigned short* __restrict__ pe, const int* __restrict__ dflag) {
  bool f32 = *dflag > 128;
  int n = blockIdx.x * blockDim.x + threadIdx.x;
  if (n >= N_NODES) return;
  float p[4];
  for (int j = 0; j < 4; ++j) p[j] = ldf(pos, (size_t)n * 4 + j, f32);
  for (int i = 0; i < 4; ++i) {
    float acc = 0.f;
    for (int j = 0; j < 4; ++j) acc += p[j] * ldf(wpe, i * 4 + j, f32);  // pos @ Wpe.T
    pe[(size_t)n * 4 + i] = f2b(acc);
  }
}

// ---------------- aggregation (CSR gather, 4-way edge ILP) ----------------
__global__ void k_agg(const unsigned short* __restrict__ in,
                      const int* __restrict__ offs, const int* __restrict__ csr,
                      const float* __restrict__ dinv,
                      unsigned short* __restrict__ out, int nrows,
                      const int* __restrict__ map, int relu) {
  const int lane = threadIdx.x & 63;
  const int g = lane >> 4;
  const int li = lane & 15;
  int gw = (blockIdx.x * blockDim.x + threadIdx.x) >> 6;
  int nw = (gridDim.x * blockDim.x) >> 6;
  for (int i = gw; i < nrows; i += nw) {
    int n = map ? map[i] : i;
    int b = offs[n], e = offs[n + 1];
    float a[8] = {0.f, 0.f, 0.f, 0.f, 0.f, 0.f, 0.f, 0.f};
    for (int j = b + g; j < e; j += 4) {
      int s = csr[j];
      const uint4 v =
          *reinterpret_cast<const uint4*>(in + (size_t)s * 128 + li * 8);
      a[0] += b2f((unsigned short)(v.x & 0xffffu));
      a[1] += b2f((unsigned short)(v.x >> 16));
      a[2] += b2f((unsigned short)(v.y & 0xffffu));
      a[3] += b2f((unsigned short)(v.y >> 16));
      a[4] += b2f((unsigned short)(v.z & 0xffffu));
      a[5] += b2f((unsigned short)(v.z >> 16));
      a[6] += b2f((unsigned short)(v.w & 0xffffu));
      a[7] += b2f((unsigned short)(v.w >> 16));
    }
#pragma unroll
    for (int c = 0; c < 8; ++c) {
      a[c] += __shfl_xor(a[c], 16);
      a[c] += __shfl_xor(a[c], 32);
    }
    if (g == 0) {
      float sc = dinv[n];
#pragma unroll
      for (int c = 0; c < 8; ++c) {
        a[c] *= sc;
        if (relu) a[c] = fmaxf(a[c], 0.f);
      }
      uint4 o;
      o.x = (unsigned int)f2b(a[0]) | ((unsigned int)f2b(a[1]) << 16);
      o.y = (unsigned int)f2b(a[2]) | ((unsigned int)f2b(a[3]) << 16);
      o.z = (unsigned int)f2b(a[4]) | ((unsigned int)f2b(a[5]) << 16);
      o.w = (unsigned int)f2b(a[6]) | ((unsigned int)f2b(a[7]) << 16);
      *reinterpret_cast<uint4*>(out + (size_t)i * 128 + li * 8) = o;
    }
  }
}

// ---------------- GEMMs (bf16 MFMA 16x16x32) ----------------
template <int NT, int KS>
__global__ void __launch_bounds__(256) k_gemm_in(const void* __restrict__ A,
                                                 const unsigned short* __restrict__ BT,
                                                 unsigned short* __restrict__ C, int M,
                                                 int ldb,
                                                 const int* __restrict__ dflag) {
  bool f32 = *dflag > 128;
  const int wid = threadIdx.x >> 6;
  const int lane = threadIdx.x & 63;
  const int lr = lane & 15;
  const int q = lane >> 4;
  const int m0 = blockIdx.x * 64 + wid * 16;
  if (m0 >= M) return;
  f32x4 acc[NT];
#pragma unroll
  for (int i = 0; i < NT; ++i) acc[i] = f32x4{0.f, 0.f, 0.f, 0.f};
  const size_t abase = (size_t)(m0 + lr) * (KS * 32) + q * 8;
#pragma unroll
  for (int ks = 0; ks < KS; ++ks) {
    bf16x8 a = ld8d(A, abase + ks * 32, f32);
#pragma unroll
    for (int nt = 0; nt < NT; ++nt) {
      bf16x8 b = ld8(BT + (size_t)(nt * 16 + lr) * ldb + ks * 32 + q * 8);
      acc[nt] = mfma16(a, b, acc[nt]);
    }
  }
#pragma unroll
  for (int nt = 0; nt < NT; ++nt)
#pragma unroll
    for (int r = 0; r < 4; ++r)
      C[(size_t)(m0 + q * 4 + r) * (NT * 16) + nt * 16 + lr] = f2b(acc[nt][r]);
}

// pure-bf16 GEMM (safe in-place C==A: wave reads only its own 16-row slab)
template <int NT, int KS>
__global__ void __launch_bounds__(256) k_gemm(const unsigned short* __restrict__ A,
                                              const unsigned short* __restrict__ BT,
                                              unsigned short* __restrict__ C, int M,
                                              int ldb) {
  const int wid = threadIdx.x >> 6;
  const int lane = threadIdx.x & 63;
  const int lr = lane & 15;
  const int q = lane >> 4;
  const int m0 = blockIdx.x * 64 + wid * 16;
  if (m0 >= M) return;
  f32x4 acc[NT];
#pragma unroll
  for (int i = 0; i < NT; ++i) acc[i] = f32x4{0.f, 0.f, 0.f, 0.f};
  const unsigned short* arow = A + (size_t)(m0 + lr) * (KS * 32) + q * 8;
#pragma unroll
  for (int ks = 0; ks < KS; ++ks) {
    bf16x8 a = ld8(arow + ks * 32);
#pragma unroll
    for (int nt = 0; nt < NT; ++nt) {
      bf16x8 b = ld8(BT + (size_t)(nt * 16 + lr) * ldb + ks * 32 + q * 8);
      acc[nt] = mfma16(a, b, acc[nt]);
    }
  }
#pragma unroll
  for (int nt = 0; nt < NT; ++nt)
#pragma unroll
    for (int r = 0; r < 4; ++r)
      C[(size_t)(m0 + q * 4 + r) * (NT * 16) + nt * 16 + lr] = f2b(acc[nt][r]);
}

// target-embedding GEMM: bf16 A -> dual-dtype store into d_out at elem_off
template <int NT, int KS>
__global__ void __launch_bounds__(256) k_gemm_out(const unsigned short* __restrict__ A,
                                                  const unsigned short* __restrict__ BT,
                                                  void* __restrict__ C, size_t elem_off,
                                                  int M, int ldb,
                                                  const int* __restrict__ dflag) {
  bool f32 = *dflag > 128;
  const int wid = threadIdx.x >> 6;
  const int lane = threadIdx.x & 63;
  const int lr = lane & 15;
  const int q = lane >> 4;
  const int m0 = blockIdx.x * 64 + wid * 16;
  if (m0 >= M) return;
  f32x4 acc[NT];
#pragma unroll
  for (int i = 0; i < NT; ++i) acc[i] = f32x4{0.f, 0.f, 0.f, 0.f};
  const unsigned short* arow = A + (size_t)(m0 + lr) * (KS * 32) + q * 8;
#pragma unroll
  for (int ks = 0; ks < KS; ++ks) {
    bf16x8 a = ld8(arow + ks * 32);
#pragma unroll
    for (int nt = 0; nt < NT; ++nt) {
      bf16x8 b = ld8(BT + (size_t)(nt * 16 + lr) * ldb + ks * 32 + q * 8);
      acc[nt] = mfma16(a, b, acc[nt]);
    }
  }
#pragma unroll
  for (int nt = 0; nt < NT; ++nt)
#pragma unroll
    for (int r = 0; r < 4; ++r) {
      size_t idx = elem_off + (size_t)(m0 + q * 4 + r) * (NT * 16) + nt * 16 + lr;
      if (f32) ((float*)C)[idx] = acc[nt][r];
      else     ((unsigned short*)C)[idx] = f2b(acc[nt][r]);
    }
}

// ---------------- fused predictor ----------------
// z@W1z+b1 precomputed (zconst) -> K shrinks 224->160 (128 ctx + 8 pe + pad):
// L1 MFMAs 112->80/wave, staged w1 114688->81920 B, LDS 59392->50688 B
// => 3 blocks/CU instead of 2.
// hid is stored sigma-permuted (sigma(k)=(k%16)*16+k/16) so the C->A transform
// is 8 packed ds_write_b128 per wave instead of 64 conflicting ds_write_b16;
// w2T columns are pre-permuted by the same involution at transpose time.
__global__ void __launch_bounds__(256) k_pred(
    const unsigned short* __restrict__ ctx, const unsigned short* __restrict__ pe,
    const int* __restrict__ pair_s, const int* __restrict__ pair_t,
    const int* __restrict__ tn, const unsigned short* __restrict__ w1T,
    const float* __restrict__ zc, const unsigned short* __restrict__ w2T,
    const void* __restrict__ b2, const void* __restrict__ pmask,
    void* __restrict__ out, const int* __restrict__ dflag) {
  bool f32 = *dflag > 128;
  __shared__ __align__(16) char smem[50688];         // max(w1 half 43008, shH+w2 qtr)
  unsigned short* w1L = (unsigned short*)smem;       // [128][168] = 43008 B
  unsigned short* shH = (unsigned short*)smem;       // [64][264]  = 33792 B
  unsigned short* w2L = (unsigned short*)(smem + 33792);  // [32][264] = 16896 B

  const int tid = threadIdx.x;
  const int wid = tid >> 6;
  const int lane = tid & 63;
  const int lr = lane & 15;
  const int q = lane >> 4;
  const int m0 = blockIdx.x * 64 + wid * 16;
  const int row = m0 + lr;
  const int s = pair_s[row];
  const int tno = tn[pair_t[row]];
  const unsigned short* ctxrow = ctx + (size_t)s * 128 + q * 8;

  // ---- build feat A-fragments once (regs): [ctx(128) | pe_s pe_t (8) | 0] ----
  bf16x8 af[5];
#pragma unroll
  for (int ks = 0; ks < 5; ++ks) {
    const int kb = ks * 32 + q * 8;
    if (kb < 128) {
      af[ks] = ld8(ctxrow + ks * 32);
    } else if (kb == 128) {
      union { bf16x8 v; unsigned long long d[2]; } u;
      u.d[0] = *reinterpret_cast<const unsigned long long*>(pe + (size_t)s * 4);
      u.d[1] = *reinterpret_cast<const unsigned long long*>(pe + (size_t)tno * 4);
      af[ks] = u.v;
    } else {
      union { bf16x8 v; unsigned long long d[2]; } u;
      u.d[0] = 0; u.d[1] = 0;
      af[ks] = u.v;
    }
  }

  // ---- layer 1: two staged halves of w1 (128 hidden rows each) ----
  f32x4 acc[16];
#pragma unroll
  for (int i = 0; i < 16; ++i) acc[i] = f32x4{0.f, 0.f, 0.f, 0.f};
  for (int h = 0; h < 2; ++h) {
#pragma unroll
    for (int it = 0; it < 10; ++it) {           // 2560 uint4 / 256 thr
      int idx = it * 256 + tid;
      int r = idx / 20, c8 = idx % 20;          // 20 uint4 per 160-short row
      *reinterpret_cast<uint4*>(w1L + r * 168 + c8 * 8) =
          *reinterpret_cast<const uint4*>(w1T + (size_t)(h * 128 + r) * 160 + c8 * 8);
    }
    __syncthreads();
#pragma unroll
    for (int ks = 0; ks < 5; ++ks)
#pragma unroll
      for (int nt = 0; nt < 8; ++nt) {
        bf16x8 b = ld8(w1L + (nt * 16 + lr) * 168 + ks * 32 + q * 8);
        acc[h * 8 + nt] = mfma16(af[ks], b, acc[h * 8 + nt]);
      }
    __syncthreads();
  }

  // ---- zconst bias + relu -> shH (sigma-permuted cols, packed b128 writes) ----
  // lane holds acc[C][r] for col = C*16+lr ; store at h' = lr*16 + C
  float zcv[16];
#pragma unroll
  for (int c = 0; c < 16; ++c) zcv[c] = zc[c * 16 + lr];
#pragma unroll
  for (int r = 0; r < 4; ++r) {
    unsigned int w[8];
#pragma unroll
    for (int p = 0; p < 8; ++p) {
      float v0 = fmaxf(acc[2 * p][r] + zcv[2 * p], 0.f);
      float v1 = fmaxf(acc[2 * p + 1][r] + zcv[2 * p + 1], 0.f);
      w[p] = (unsigned int)f2b(v0) | ((unsigned int)f2b(v1) << 16);
    }
    unsigned short* dstp = shH + (size_t)(wid * 16 + q * 4 + r) * 264 + lr * 16;
    uint4 o0; o0.x = w[0]; o0.y = w[1]; o0.z = w[2]; o0.w = w[3];
    uint4 o1; o1.x = w[4]; o1.y = w[5]; o1.z = w[6]; o1.w = w[7];
    *reinterpret_cast<uint4*>(dstp) = o0;
    *reinterpret_cast<uint4*>(dstp + 8) = o1;
  }
  // stage w2 quarter 0
#pragma unroll
  for (int it = 0; it < 4; ++it) {              // 1024 uint4 / 256 thr
    int idx = it * 256 + tid;
    int r = idx >> 5, c8 = idx & 31;            // 32 uint4 per 256-short row
    *reinterpret_cast<uint4*>(w2L + r * 264 + c8 * 8) =
        *reinterpret_cast<const uint4*>(w2T + (size_t)r * 256 + c8 * 8);
  }
  __syncthreads();

  // ---- hid A-fragments once (regs; permuted index space matches w2T') ----
  bf16x8 af2[8];
  const unsigned short* hrow = shH + (size_t)(wid * 16 + lr) * 264 + q * 8;
#pragma unroll
  for (int ks = 0; ks < 8; ++ks) af2[ks] = ld8(hrow + ks * 32);

  // ---- layer 2: four staged quarters of w2 ----
  f32x4 acc2[8];
#pragma unroll
  for (int i = 0; i < 8; ++i) acc2[i] = f32x4{0.f, 0.f, 0.f, 0.f};
  for (int ph = 0; ph < 4; ++ph) {
    if (ph) {
      __syncthreads();                          // prior compute done
#pragma unroll
      for (int it = 0; it < 4; ++it) {
        int idx = it * 256 + tid;
        int r = idx >> 5, c8 = idx & 31;
        *reinterpret_cast<uint4*>(w2L + r * 264 + c8 * 8) =
            *reinterpret_cast<const uint4*>(w2T + (size_t)(ph * 32 + r) * 256 + c8 * 8);
      }
      __syncthreads();
    }
#pragma unroll
    for (int nt2 = 0; nt2 < 2; ++nt2)
#pragma unroll
      for (int ks = 0; ks < 8; ++ks) {
        bf16x8 b = ld8(w2L + (nt2 * 16 + lr) * 264 + ks * 32 + q * 8);
        acc2[ph * 2 + nt2] = mfma16(af2[ks], b, acc2[ph * 2 + nt2]);
      }
  }

  // ---- epilogue ----
#pragma unroll
  for (int nt = 0; nt < 8; ++nt) {
    float bias = ldf(b2, nt * 16 + lr, f32);
#pragma unroll
    for (int r = 0; r < 4; ++r) {
      int rr = m0 + q * 4 + r;
      float mk = ldf(pmask, rr, f32);
      float v = (acc2[nt][r] + bias) * mk;
      size_t idx = (size_t)rr * 128 + nt * 16 + lr;
      if (f32) ((float*)out)[idx] = v;
      else     ((unsigned short*)out)[idx] = f2b(v);
    }
  }
}

extern "C" void kernel_launch(void* const* d_in, const int* in_sizes, int n_in,
                              void* d_out, int out_size, void* d_ws, size_t ws_size,
                              hipStream_t stream) {
  const void* x    = d_in[0];
  const void* mx   = d_in[1];
  const void* pos  = d_in[2];
  const int* esrc  = (const int*)d_in[3];
  const int* edst  = (const int*)d_in[4];
  const int* tn    = (const int*)d_in[5];
  const int* pt    = (const int*)d_in[6];
  const int* ps    = (const int*)d_in[7];
  const void* pmask= d_in[8];
  const void* W1t  = d_in[9];
  const void* W2t  = d_in[10];
  const void* W1c  = d_in[11];
  const void* W2c  = d_in[12];
  const void* Wpe  = d_in[13];
  const void* z    = d_in[14];
  const void* Wp1  = d_in[15];
  const void* bp1  = d_in[16];
  const void* Wp2  = d_in[17];
  const void* bp2  = d_in[18];

  char* w = (char*)d_ws;
  auto carve = [&](size_t bytes) -> void* {
    void* p = (void*)w;
    w += (bytes + 255) & ~(size_t)255;
    return p;
  };
  int*   dflag = (int*)carve(256);
  int*   offs  = (int*)carve((N_NODES + 1) * sizeof(int));
  int*   cur   = (int*)carve(N_NODES * sizeof(int));
  int*   part  = (int*)carve(4096);
  int*   csr   = (int*)carve(E_EDGES * sizeof(int));
  float* dinv  = (float*)carve(N_NODES * sizeof(float));
  float* zc    = (float*)carve(256 * sizeof(float));
  unsigned short* bufA  = (unsigned short*)carve((size_t)N_NODES * 128 * 2);
  unsigned short* peB   = (unsigned short*)carve((size_t)N_NODES * 4 * 2);
  unsigned short* gt    = (unsigned short*)carve((size_t)T_TGT * 128 * 2);
  unsigned short* w1tT  = (unsigned short*)carve(128 * 128 * 2);
  unsigned short* w2tT  = (unsigned short*)carve(128 * 128 * 2);
  unsigned short* w1cT  = (unsigned short*)carve(128 * 128 * 2);
  unsigned short* w2cT  = (unsigned short*)carve(128 * 128 * 2);
  unsigned short* wp1T  = (unsigned short*)carve(256 * 160 * 2);
  unsigned short* wp2T  = (unsigned short*)carve(128 * 256 * 2);
  // bufB overlays d_out's pred region (>= 25.6MB in both dtypes; pred rows
  // are written last, so earlier uses are dead by then).
  unsigned short* bufB = (unsigned short*)d_out;
  // rank overlays bufA: only live between k_hist and k_fill, which both
  // precede the first GEMM write into bufA.
  int* rank = (int*)bufA;

  // ---- dtype sniff ----
  hipMemsetAsync(dflag, 0, sizeof(int), stream);
  k_sniff<<<1, 256, 0, stream>>>((const unsigned int*)x, dflag);

  // ---- graph prep (CSR by dst + degrees) ----
  hipMemsetAsync(cur, 0, N_NODES * sizeof(int), stream);
  k_hist<<<1024, 256, 0, stream>>>(edst, cur, rank);
  k_deginv<<<(N_NODES + 255) / 256, 256, 0, stream>>>(cur, dinv);
  k_scan_a<<<NCHUNK, 256, 0, stream>>>(cur, part);
  k_scan_b<<<1, 1, 0, stream>>>(part, offs);
  k_scan_c<<<NCHUNK, 256, 0, stream>>>(cur, part, offs);
  k_fill<<<1024, 256, 0, stream>>>(esrc, edst, offs, rank, csr);

  // ---- weight transposes (B^T layouts, dual-dtype reads) ----
  k_transpose<<<64, 256, 0, stream>>>(W1t, w1tT, 128, 128, 128, 128 * 128, dflag);
  k_transpose<<<64, 256, 0, stream>>>(W2t, w2tT, 128, 128, 128, 128 * 128, dflag);
  k_transpose<<<64, 256, 0, stream>>>(W1c, w1cT, 128, 128, 128, 128 * 128, dflag);
  k_transpose<<<64, 256, 0, stream>>>(W2c, w2cT, 128, 128, 128, 128 * 128, dflag);
  k_tr_wp1<<<160, 256, 0, stream>>>(Wp1, wp1T, dflag);
  k_tr_wp2<<<128, 256, 0, stream>>>(Wp2, wp2T, dflag);
  k_zconst<<<1, 256, 0, stream>>>(z, Wp1, bp1, zc, dflag);

  k_pe<<<(N_NODES + 255) / 256, 256, 0, stream>>>(pos, Wpe, peB, dflag);

  const int gemmN_grid = (N_NODES + 63) / 64;  // 1563
  const int aggN_grid = 4096;   // 16384 waves: full occupancy + grid-stride
  const int aggT_grid = 1024;   // 4096 rows, 1 row/wave

  // ---- target GCN: emb = (agg(relu(agg(x@W1t)))[targets]) @ W2t ----
  k_gemm_in<8, 4><<<gemmN_grid, 256, 0, stream>>>(x, w1tT, bufA, N_NODES, 128, dflag);
  k_agg<<<aggN_grid, 256, 0, stream>>>(bufA, offs, csr, dinv, bufB, N_NODES, nullptr, 1);
  k_agg<<<aggT_grid, 256, 0, stream>>>(bufB, offs, csr, dinv, gt, T_TGT, tn, 0);
  k_gemm_out<8, 4><<<T_TGT / 64, 256, 0, stream>>>(gt, w2tT, d_out,
                                                   (size_t)P_PAIRS * 128, T_TGT, 128,
                                                   dflag);

  // ---- context GCN: ctx = agg(relu(agg(mx@W1c))) @ W2c ----
  k_gemm_in<8, 4><<<gemmN_grid, 256, 0, stream>>>(mx, w1cT, bufA, N_NODES, 128, dflag);
  k_agg<<<aggN_grid, 256, 0, stream>>>(bufA, offs, csr, dinv, bufB, N_NODES, nullptr, 1);
  k_agg<<<aggN_grid, 256, 0, stream>>>(bufB, offs, csr, dinv, bufA, N_NODES, nullptr, 0);
  k_gemm<8, 4><<<gemmN_grid, 256, 0, stream>>>(bufA, w2cT, bufA, N_NODES, 128);

  // ---- fused predictor (reads bufA in ws; writes pred region of d_out) ----
  k_pred<<<P_PAIRS / 64, 256, 0, stream>>>(bufA, peB, ps, pt, tn, wp1T, zc, wp2T,
                                           bp2, pmask, d_out, dflag);
}